// Round 1
// baseline (344.054 us; speedup 1.0000x reference)
//
#include <hip/hip_runtime.h>
#include <math.h>

namespace {
constexpr int B = 512, S = 64, K = 8, D = 16, NR = 64, NSTEPS = 100, NUNITS = 128;
}

// Intra-wave LDS fence: same-wave DS ops complete in order; this waits for
// all outstanding LDS ops and stops the compiler reordering LDS accesses
// across it. Replaces __syncthreads() for wave-private LDS.
#define WAVE_LDS_FENCE() __asm__ volatile("s_waitcnt lgkmcnt(0)" ::: "memory")

// Load 16 consecutive floats (global or LDS, 16B-aligned) into a float[16].
#define LOAD16(dst, ptr)                                                     \
    {                                                                        \
        const float4* _p = (const float4*)(ptr);                             \
        float4 _a = _p[0], _b = _p[1], _c = _p[2], _d = _p[3];               \
        dst[0] = _a.x;  dst[1] = _a.y;  dst[2] = _a.z;  dst[3] = _a.w;       \
        dst[4] = _b.x;  dst[5] = _b.y;  dst[6] = _b.z;  dst[7] = _b.w;       \
        dst[8] = _c.x;  dst[9] = _c.y;  dst[10] = _c.z; dst[11] = _c.w;      \
        dst[12] = _d.x; dst[13] = _d.y; dst[14] = _d.z; dst[15] = _d.w;      \
    }

// ---------------------------------------------------------------------------
// Fused prep: (t<64) w_tab[b][r] user-relation scores; (64<=t<128) hop-1
// index prefetch e1s/r0s; (b==0, t in [128,228)) diffusion alpha schedule.
// ---------------------------------------------------------------------------
__global__ __launch_bounds__(256) void k_prep_all(
    const float* __restrict__ usr_emb, const float* __restrict__ rel_emb,
    const int* __restrict__ u, const int* __restrict__ click_seq,
    const int* __restrict__ adj_ent, const int* __restrict__ adj_rel,
    float* __restrict__ w_tab, int* __restrict__ e1s, int* __restrict__ r0s,
    float* __restrict__ sa, float* __restrict__ so)
{
    int b = blockIdx.x, t = threadIdx.x;
    if (t < 64) {
        const float* ur = usr_emb + (long)u[b] * D;
        const float* rr = rel_emb + t * D;
        float s = 0.f;
#pragma unroll
        for (int d = 0; d < D; ++d) s += ur[d] * rr[d];
        w_tab[b * NR + t] = s * (1.0f / 16.0f);
    } else if (t < 128) {
        int p = b * S + (t - 64);
        int e0 = click_seq[p];
        const int4* ae = (const int4*)(adj_ent + (long)e0 * K);
        const int4* ar = (const int4*)(adj_rel + (long)e0 * K);
        int4 a0 = ae[0], a1 = ae[1], b0 = ar[0], b1 = ar[1];
        int4* oe = (int4*)(e1s + (long)p * K);
        int4* orr = (int4*)(r0s + (long)p * K);
        oe[0] = a0; oe[1] = a1;
        orr[0] = b0; orr[1] = b1;
    } else if (b == 0 && (t - 128) < NSTEPS) {
        int i = t - 128;
        float prod = 1.0f;
        for (int jj = 0; jj <= i; ++jj) {
            float x = -6.0f + (float)jj * (12.0f / 99.0f);
            float sig = 1.0f / (1.0f + expf(-x));
            prod *= (1.0f - (sig * (0.005f - 1e-5f) + 1e-5f));
        }
        sa[i] = sqrtf(prod);
        so[i] = sqrtf(1.0f - prod);
    }
}

// ---------------------------------------------------------------------------
// KGCN R6: same verified wave-private dataflow as R5, but the epilogue
// matvecs are register-resident:
//   - agg_W stored TRANSPOSED in LDS (stride 20: 16B-aligned rows, odd-ish
//     bank spread); each lane hoists its output column into 16 VGPRs once
//     (4x ds_read_b128) and reuses it for h1(x2), h0 and the final matvec.
//   - Ms rows read as 4x ds_read_b128 broadcast (was 16x ds_read_b32/output).
//   - h1/h0 stay in registers; M1 = h0 + sum_k p0[k] h1[k] computed with a
//     shfl_xor(16/32) butterfly (p0 via 2 __shfl), killing h1s/h0s/p0s LDS.
//   - user-relation scores read straight from w_tab (L1-hot 256B row),
//     removing the wb staging and one of the three fences.
// LDS-pipe ops/lane drop from ~120 to ~60.
// ---------------------------------------------------------------------------
__global__ __launch_bounds__(256) void k_kgcn(
    const float* __restrict__ ent_emb,
    const float* __restrict__ w_tab,      // [B, NR]
    const int* __restrict__ click_seq,    // [B*S]
    const int* __restrict__ adj_ent,      // [NE, K]
    const int* __restrict__ adj_rel,      // [NE, K]
    const int* __restrict__ e1s,          // [B*S*K] precomputed
    const int* __restrict__ r0s,          // [B*S*K] precomputed
    const float* __restrict__ agg_W,      // [D, D]
    const float* __restrict__ agg_b,      // [D]
    float* __restrict__ item)             // [B*S, D]
{
    __shared__ __attribute__((aligned(16))) float Wt[4][D][20];  // Wt[w][col][row]
    __shared__ __attribute__((aligned(16))) float Ms[4][K][20];
    __shared__ __attribute__((aligned(16))) float A0s[4][D];
    __shared__ __attribute__((aligned(16))) float M1s[4][D];
    __shared__ float bs[4][D];

    const int tid = threadIdx.x;
    const int w = tid >> 6;             // wave in block, 0..3
    const int lane = tid & 63;
    const int p = blockIdx.x * 4 + w;   // pair id = b*S + s (64%4==0 -> same b)
    const int b = p >> 6;
    const int k = lane >> 3, j = lane & 7;

    // ---- index loads (e1s/r0s warm from k_prep_all), then the wide gathers
    const int e0 = click_seq[p];
    const int e1k = e1s[(long)p * K + k];
    const int r0k = r0s[(long)p * K + k];
    const int e2kj = adj_ent[(long)e1k * K + j];
    const int r1kj = adj_rel[(long)e1k * K + j];

    // ---- per-wave staging: transposed W + bias (read only after the fence)
    {
        const float4 wv = ((const float4*)agg_W)[lane];     // row lane>>2, cols (lane&3)*4..
        int row = lane >> 2, col = (lane & 3) * 4;
        Wt[w][col][row]     = wv.x;
        Wt[w][col + 1][row] = wv.y;
        Wt[w][col + 2][row] = wv.z;
        Wt[w][col + 3][row] = wv.w;
        if (lane < D) bs[w][lane] = agg_b[lane];
    }

    // ---- user-relation scores straight from global (row is L1-hot: all 4
    // waves of this block share b, row = 256B)
    const float* wrow = w_tab + (long)b * NR;
    const float s1 = wrow[r1kj];
    const float s0 = wrow[r0k];

    // ---- hop-1 softmax over j (masks 1,2,4 stay inside the 8-lane j-group)
    float m1x = s1;
    m1x = fmaxf(m1x, __shfl_xor(m1x, 1));
    m1x = fmaxf(m1x, __shfl_xor(m1x, 2));
    m1x = fmaxf(m1x, __shfl_xor(m1x, 4));
    float ex = expf(s1 - m1x);
    float den = ex;
    den += __shfl_xor(den, 1);
    den += __shfl_xor(den, 2);
    den += __shfl_xor(den, 4);
    float p1 = ex / den;

    // ---- gather rows: q2 (own), q1 (group-shared), q0 (wave-shared)
    float q2r[16], q1r[16], q0r[16];
    LOAD16(q2r, ent_emb + (long)e2kj * D);
    LOAD16(q1r, ent_emb + (long)e1k * D);
    LOAD16(q0r, ent_emb + (long)e0 * D);

    // ---- hop-1 j-reduction (reduce-scatter, masks 1,2,4). Lane keeps the
    // half it will own; final 2 dims at dbase = 8(j&1)+4(j>>1&1)+2(j>>2&1).
    {
        float cur[16];
#pragma unroll
        for (int d = 0; d < 16; ++d) cur[d] = p1 * q2r[d];
        const bool b0 = (lane & 1), b1 = (lane & 2), b2 = (lane & 4);
        float n8[8];
#pragma unroll
        for (int d = 0; d < 8; ++d) {
            float snd = b0 ? cur[d] : cur[d + 8];
            float kp  = b0 ? cur[d + 8] : cur[d];
            n8[d] = kp + __shfl_xor(snd, 1);
        }
        float n4[4];
#pragma unroll
        for (int d = 0; d < 4; ++d) {
            float snd = b1 ? n8[d] : n8[d + 4];
            float kp  = b1 ? n8[d + 4] : n8[d];
            n4[d] = kp + __shfl_xor(snd, 2);
        }
        float a0 = (b2 ? n4[2] : n4[0]) + __shfl_xor(b2 ? n4[0] : n4[2], 4);
        float a1 = (b2 ? n4[3] : n4[1]) + __shfl_xor(b2 ? n4[1] : n4[3], 4);
        const int dbase = (b0 ? 8 : 0) + (b1 ? 4 : 0) + (b2 ? 2 : 0);
        // self + neigh_agg, 8B-aligned (dbase even, row stride 80B)
        *(float2*)&Ms[w][k][dbase] = make_float2(q1r[dbase] + a0, q1r[dbase + 1] + a1);
    }

    // ---- hop-0 softmax over k (masks 8,16,32 keep j fixed)
    float m0 = s0;
    m0 = fmaxf(m0, __shfl_xor(m0, 8));
    m0 = fmaxf(m0, __shfl_xor(m0, 16));
    m0 = fmaxf(m0, __shfl_xor(m0, 32));
    float e0x = expf(s0 - m0);
    float d0 = e0x;
    d0 += __shfl_xor(d0, 8);
    d0 += __shfl_xor(d0, 16);
    d0 += __shfl_xor(d0, 32);
    float p0 = e0x / d0;

    // ---- ag0 = sum_k p0_k * q1[k]: reduce-scatter over k (masks 8,16,32);
    // identical values across j, so j==0 lanes deposit the 16 dims in A0s.
    {
        float cur[16];
#pragma unroll
        for (int d = 0; d < 16; ++d) cur[d] = p0 * q1r[d];
        const bool c0 = (lane & 8), c1 = (lane & 16), c2 = (lane & 32);
        float n8[8];
#pragma unroll
        for (int d = 0; d < 8; ++d) {
            float snd = c0 ? cur[d] : cur[d + 8];
            float kp  = c0 ? cur[d + 8] : cur[d];
            n8[d] = kp + __shfl_xor(snd, 8);
        }
        float n4[4];
#pragma unroll
        for (int d = 0; d < 4; ++d) {
            float snd = c1 ? n8[d] : n8[d + 4];
            float kp  = c1 ? n8[d + 4] : n8[d];
            n4[d] = kp + __shfl_xor(snd, 16);
        }
        float a0 = (c2 ? n4[2] : n4[0]) + __shfl_xor(c2 ? n4[0] : n4[2], 32);
        float a1 = (c2 ? n4[3] : n4[1]) + __shfl_xor(c2 ? n4[1] : n4[3], 32);
        const int dbase = (c0 ? 8 : 0) + (c1 ? 4 : 0) + (c2 ? 2 : 0);
        if (j == 0) *(float2*)&A0s[w][dbase] = make_float2(a0, a1);
    }
    WAVE_LDS_FENCE();   // Wt, bs, Ms, A0s visible to this wave

    const int ddl = lane & 15;          // output dim this lane owns
    const int g = lane >> 4;            // k-group: handles k=g and k=g+4

    // ---- hoist W column ddl into registers (reused by h1 x2, h0, final)
    float wc[16];
    LOAD16(wc, &Wt[w][ddl][0]);
    const float bias = bs[w][ddl];

    // ---- h1[g][ddl], h1[g+4][ddl]: Ms rows via b128 broadcast reads
    float h1a, h1b;
    {
        float mr[16];
        LOAD16(mr, &Ms[w][g][0]);
        float acc = bias;
#pragma unroll
        for (int i = 0; i < 16; ++i) acc += mr[i] * wc[i];
        h1a = 1.0f / (1.0f + expf(-acc));
    }
    {
        float mr[16];
        LOAD16(mr, &Ms[w][g + 4][0]);
        float acc = bias;
#pragma unroll
        for (int i = 0; i < 16; ++i) acc += mr[i] * wc[i];
        h1b = 1.0f / (1.0f + expf(-acc));
    }

    // ---- h0[ddl] = sigmoid((q0 + ag0) @ W + b), computed by every lane
    float h0v;
    {
        float ar[16];
        LOAD16(ar, &A0s[w][0]);
        float acc = bias;
#pragma unroll
        for (int i = 0; i < 16; ++i) acc += (q0r[i] + ar[i]) * wc[i];
        h0v = 1.0f / (1.0f + expf(-acc));
    }

    // ---- M1[ddl] = h0 + sum_k p0[k] h1[k][ddl] via shfl butterfly.
    // p0 for k=g lives at lane 8g; for k=g+4 at lane 8g+32.
    const float p0a = __shfl(p0, g * 8);
    const float p0b = __shfl(p0, g * 8 + 32);
    float part = p0a * h1a + p0b * h1b;
    part += __shfl_xor(part, 16);
    part += __shfl_xor(part, 32);
    const float m1v = h0v + part;
    if (lane < D) M1s[w][lane] = m1v;
    WAVE_LDS_FENCE();   // M1s ready (wave-private)

    // ---- final: relu(tanh(M1 @ W + b))
    {
        float mr[16];
        LOAD16(mr, &M1s[w][0]);
        float acc = bias;
#pragma unroll
        for (int i = 0; i < 16; ++i) acc += mr[i] * wc[i];
        if (lane < D) item[(long)p * D + lane] = fmaxf(tanhf(acc), 0.0f);
    }
}

// ---------------------------------------------------------------------------
// Fused tail R6 (one block per b, 256 threads):
//   - diffusion MLP 128-wide layers split-K across 2 half-threads (h=tid>>7):
//     chain length halves, waves/CU double (4 -> 8).
//   - fusion head runs CONCURRENTLY on waves 2-3 (sm stage, fus, hid, feat,
//     final dot are slotted into the MLP's barrier phases instead of after).
// ---------------------------------------------------------------------------
__global__ __launch_bounds__(256) void k_tail(
    const float* __restrict__ item,     // [B*S, D]
    const float* __restrict__ fc1_W, const float* __restrict__ fc1_b,
    const float* __restrict__ fc2_W, const float* __restrict__ fc2_b,
    const float* __restrict__ ent_emb, const int* __restrict__ v,
    const float* __restrict__ usr_emb, const float* __restrict__ noise_e,
    const int* __restrict__ u, const int* __restrict__ t_arr,
    const float* __restrict__ W1, const float* __restrict__ b1,
    const float* __restrict__ W2, const float* __restrict__ b2,
    const float* __restrict__ W3, const float* __restrict__ b3,
    const float* __restrict__ W4, const float* __restrict__ b4,
    const float* __restrict__ se1, const float* __restrict__ se2,
    const float* __restrict__ se3,
    const float* __restrict__ sa, const float* __restrict__ so,
    float* __restrict__ out)            // [B, 17]
{
    __shared__ float x0[D];
    __shared__ float v1[NUNITS], v2[NUNITS], v3[NUNITS];
    __shared__ float pp[2][NUNITS];
    __shared__ float sm[S][D + 1];
    __shared__ float fus[2 * D];
    __shared__ float hid[64];
    __shared__ float feat_s[D];

    const int b = blockIdx.x, tid = threadIdx.x;
    const int t = tid & 127, h = tid >> 7;
    const int ts = t_arr[b];

    // ---- phase 0: stage x0 (wave 0) + sm (wave 2)
    if (tid < D)
        x0[tid] = usr_emb[(long)u[b] * D + tid] * sa[ts] + noise_e[(long)b * D + tid] * so[ts];
    if (tid >= 128 && tid < 192) {
        int ss = tid - 128;
        const float4* ip = (const float4*)(item + ((long)b * S + ss) * D);
        float4 r0 = ip[0], r1 = ip[1], r2 = ip[2], r3 = ip[3];
        sm[ss][0]=r0.x;  sm[ss][1]=r0.y;  sm[ss][2]=r0.z;  sm[ss][3]=r0.w;
        sm[ss][4]=r1.x;  sm[ss][5]=r1.y;  sm[ss][6]=r1.z;  sm[ss][7]=r1.w;
        sm[ss][8]=r2.x;  sm[ss][9]=r2.y;  sm[ss][10]=r2.z; sm[ss][11]=r2.w;
        sm[ss][12]=r3.x; sm[ss][13]=r3.y; sm[ss][14]=r3.z; sm[ss][15]=r3.w;
    }
    __syncthreads();

    // ---- phase 1: L1 (waves 0-1, D-wide input: no split) + fus (wave 3)
    if (h == 0) {
        float a = b1[t] + se1[(long)ts * NUNITS + t];
#pragma unroll
        for (int i = 0; i < D; ++i) a += x0[i] * W1[i * NUNITS + t];
        v1[t] = fmaxf(a, 0.0f);
    } else if (tid >= 192 && tid < 192 + D) {
        int d = tid - 192;
        float sv = 0.0f, mv = -1e30f;
#pragma unroll
        for (int ss = 0; ss < S; ++ss) {
            float x = sm[ss][d];
            sv += x;
            mv = fmaxf(mv, x);
        }
        fus[d] = fmaxf(sv, 0.0f);
        fus[D + d] = fmaxf(mv, 0.0f);
    }
    __syncthreads();

    // ---- phase 2: L2 partials (all 256; each half sums 64 of 128)
    {
        float part = 0.0f;
        const float* wp = W2 + (long)(64 * h) * NUNITS + t;
#pragma unroll 8
        for (int i = 0; i < 64; ++i) part += v1[64 * h + i] * wp[(long)i * NUNITS];
        pp[h][t] = part;
    }
    __syncthreads();

    // ---- phase 3: v2 combine (waves 0-1) + hid (wave 2)
    if (tid < NUNITS) {
        v2[tid] = fmaxf(b2[tid] + se2[(long)ts * NUNITS + tid] + pp[0][tid] + pp[1][tid], 0.0f);
    } else if (tid < 192) {
        int o = tid - 128;
        float acc = fc1_b[o];
#pragma unroll
        for (int i = 0; i < 2 * D; ++i) acc += fus[i] * fc1_W[i * 64 + o];
        hid[o] = fmaxf(acc, 0.0f);
    }
    __syncthreads();

    // ---- phase 4: L3 partials
    {
        float part = 0.0f;
        const float* wp = W3 + (long)(64 * h) * NUNITS + t;
#pragma unroll 8
        for (int i = 0; i < 64; ++i) part += v2[64 * h + i] * wp[(long)i * NUNITS];
        pp[h][t] = part;
    }
    __syncthreads();

    // ---- phase 5: v3 combine (waves 0-1) + feat (wave 3)
    if (tid < NUNITS) {
        v3[tid] = fmaxf(b3[tid] + se3[(long)ts * NUNITS + tid] + pp[0][tid] + pp[1][tid], 0.0f);
    } else if (tid >= 192 && tid < 192 + D) {
        int d = tid - 192;
        float f = fc2_b[d];
#pragma unroll
        for (int i = 0; i < 64; ++i) f += hid[i] * fc2_W[i * D + d];
        feat_s[d] = fmaxf(f, 0.0f);
    }
    __syncthreads();

    // ---- phase 6: L4 partials (wave 0, lanes<32) + final dot (wave 3)
    if (tid < 32) {
        int o = tid & 15, hh = tid >> 4;
        float acc = 0.0f;
#pragma unroll
        for (int i = 0; i < 64; ++i) acc += v3[64 * hh + i] * W4[(64 * hh + i) * D + o];
        pp[hh][o] = acc;
    } else if (tid >= 192 && tid < 192 + D) {
        int d = tid - 192;
        float gv = feat_s[d] * ent_emb[(long)v[b] * D + d];
        gv += __shfl_xor(gv, 1);
        gv += __shfl_xor(gv, 2);
        gv += __shfl_xor(gv, 4);
        gv += __shfl_xor(gv, 8);
        if (d == 0) out[(long)b * 17] = 1.0f / (1.0f + expf(-gv));
    }
    __syncthreads();

    // ---- phase 7: diffusion output (no activation on the last layer)
    if (tid < D) out[(long)b * 17 + 1 + tid] = b4[tid] + pp[0][tid] + pp[1][tid];
}

// ---------------------------------------------------------------------------
extern "C" void kernel_launch(void* const* d_in, const int* in_sizes, int n_in,
                              void* d_out, int out_size, void* d_ws, size_t ws_size,
                              hipStream_t stream) {
    const float* usr_emb = (const float*)d_in[0];
    const float* ent_emb = (const float*)d_in[1];
    const float* rel_emb = (const float*)d_in[2];
    const float* agg_W   = (const float*)d_in[3];
    const float* agg_b   = (const float*)d_in[4];
    const float* fc1_W   = (const float*)d_in[5];
    const float* fc1_b   = (const float*)d_in[6];
    const float* fc2_W   = (const float*)d_in[7];
    const float* fc2_b   = (const float*)d_in[8];
    const float* mlp_W1  = (const float*)d_in[9];
    const float* mlp_b1  = (const float*)d_in[10];
    const float* mlp_W2  = (const float*)d_in[11];
    const float* mlp_b2  = (const float*)d_in[12];
    const float* mlp_W3  = (const float*)d_in[13];
    const float* mlp_b3  = (const float*)d_in[14];
    const float* mlp_W4  = (const float*)d_in[15];
    const float* mlp_b4  = (const float*)d_in[16];
    const float* se1     = (const float*)d_in[17];
    const float* se2     = (const float*)d_in[18];
    const float* se3     = (const float*)d_in[19];
    const float* noise_e = (const float*)d_in[20];
    const int* u         = (const int*)d_in[21];
    const int* v         = (const int*)d_in[22];
    const int* click_seq = (const int*)d_in[23];
    const int* adj_ent   = (const int*)d_in[24];
    const int* adj_rel   = (const int*)d_in[25];
    const int* t         = (const int*)d_in[26];
    float* out = (float*)d_out;

    float* ws = (float*)d_ws;
    float* w_tab = ws;                         // B*NR floats
    float* sa    = w_tab + B * NR;             // 128 floats (NSTEPS used)
    float* so    = sa + 128;                   // 128 floats
    float* item  = so + 128;                   // B*S*D floats
    int*   e1s   = (int*)(item + B * S * D);   // B*S*K ints
    int*   r0s   = e1s + B * S * K;            // B*S*K ints

    k_prep_all<<<B, 256, 0, stream>>>(usr_emb, rel_emb, u, click_seq, adj_ent, adj_rel,
                                      w_tab, e1s, r0s, sa, so);
    k_kgcn<<<(B * S) / 4, 256, 0, stream>>>(ent_emb, w_tab, click_seq, adj_ent, adj_rel,
                                            e1s, r0s, agg_W, agg_b, item);
    k_tail<<<B, 256, 0, stream>>>(item, fc1_W, fc1_b, fc2_W, fc2_b, ent_emb, v,
                                  usr_emb, noise_e, u, t, mlp_W1, mlp_b1, mlp_W2, mlp_b2,
                                  mlp_W3, mlp_b3, mlp_W4, mlp_b4, se1, se2, se3, sa, so, out);
}

// Round 4
// 334.709 us; speedup vs baseline: 1.0279x; 1.0279x over previous
//
#include <hip/hip_runtime.h>
#include <math.h>

namespace {
constexpr int B = 512, S = 64, K = 8, D = 16, NR = 64, NSTEPS = 100, NUNITS = 128;
}

// clang ext-vector int4: __builtin_nontemporal_load requires a real vector
// type (HIP's int4 is a class and is rejected).
typedef int i4 __attribute__((ext_vector_type(4)));

static __device__ __forceinline__ i4 ntload4(const int* p) {
    return __builtin_nontemporal_load((const i4*)p);
}

// Intra-wave LDS fence: same-wave DS ops complete in order; this waits for
// all outstanding LDS ops and stops the compiler reordering LDS accesses
// across it. Replaces __syncthreads() for wave-private LDS.
#define WAVE_LDS_FENCE() __asm__ volatile("s_waitcnt lgkmcnt(0)" ::: "memory")

// ---------------------------------------------------------------------------
// Fused prep R9: phase A (w_tab scores / hop-1 indices / alphas), then
// phase B gathers the HOP-2 indices and PACKS (e2<<6)|r1 into ONE int32
// stream (e2 < 2e6 fits 21 bits, r1 < 64 fits 6). This removes one random
// HBM round-trip from k_kgcn's dependent chain while adding only 8 MB of
// workspace. Adjacency reads are non-temporal: single-use random 32B
// granules; keep them out of L3 so the 128 MB ent_emb table stays resident.
// ---------------------------------------------------------------------------
__global__ __launch_bounds__(256) void k_prep_all(
    const float* __restrict__ usr_emb, const float* __restrict__ rel_emb,
    const int* __restrict__ u, const int* __restrict__ click_seq,
    const int* __restrict__ adj_ent, const int* __restrict__ adj_rel,
    float* __restrict__ w_tab, int* __restrict__ e1s, int* __restrict__ r0s,
    int* __restrict__ e2r1,
    float* __restrict__ sa, float* __restrict__ so)
{
    __shared__ int e1L[S * K];
    int b = blockIdx.x, t = threadIdx.x;
    if (t < 64) {
        const float* ur = usr_emb + (long)u[b] * D;
        const float* rr = rel_emb + t * D;
        float s = 0.f;
#pragma unroll
        for (int d = 0; d < D; ++d) s += ur[d] * rr[d];
        w_tab[b * NR + t] = s * (1.0f / 16.0f);
    } else if (t < 128) {
        int s = t - 64;
        int p = b * S + s;
        int e0 = click_seq[p];
        i4 a0 = ntload4(adj_ent + (long)e0 * K);
        i4 a1 = ntload4(adj_ent + (long)e0 * K + 4);
        i4 c0 = ntload4(adj_rel + (long)e0 * K);
        i4 c1 = ntload4(adj_rel + (long)e0 * K + 4);
        *(i4*)(e1s + (long)p * K)     = a0;
        *(i4*)(e1s + (long)p * K + 4) = a1;
        *(i4*)(r0s + (long)p * K)     = c0;
        *(i4*)(r0s + (long)p * K + 4) = c1;
        *(i4*)(e1L + s * K)     = a0;
        *(i4*)(e1L + s * K + 4) = a1;
    } else if (b == 0 && (t - 128) < NSTEPS) {
        int i = t - 128;
        float prod = 1.0f;
        for (int jj = 0; jj <= i; ++jj) {
            float x = -6.0f + (float)jj * (12.0f / 99.0f);
            float sig = 1.0f / (1.0f + expf(-x));
            prod *= (1.0f - (sig * (0.005f - 1e-5f) + 1e-5f));
        }
        sa[i] = sqrtf(prod);
        so[i] = sqrtf(1.0f - prod);
    }
    __syncthreads();

    // ---- phase B: hop-2 index gather + pack. 512 (s,k) items per block,
    // 2/thread. Writes fully coalesced (thread t owns 64 contiguous bytes).
    i4* oer = (i4*)(e2r1 + (long)b * (S * K * K));
#pragma unroll
    for (int it = 0; it < 2; ++it) {
        int idx = t * 2 + it;               // (s,k): s=idx>>3, k=idx&7
        int e1k = e1L[idx];
        i4 x0 = ntload4(adj_ent + (long)e1k * K);
        i4 x1 = ntload4(adj_ent + (long)e1k * K + 4);
        i4 y0 = ntload4(adj_rel + (long)e1k * K);
        i4 y1 = ntload4(adj_rel + (long)e1k * K + 4);
        oer[idx * 2]     = (x0 << 6) | y0;   // (e2<<6)|r1, elementwise
        oer[idx * 2 + 1] = (x1 << 6) | y1;
    }
}

// ---------------------------------------------------------------------------
// KGCN R9: exact R5 body (the proven 80 µs version: 4 wave-private pairs per
// 256-thread block, zero block barriers), with ONE change: hop-2 indices
// come from the packed e2r1 stream (one coalesced 256 B/wave load) instead
// of dependent random adj_ent/adj_rel gathers. The ent_emb gather chain is
// now only ONE random round-trip deep.
// ---------------------------------------------------------------------------
__global__ __launch_bounds__(256) void k_kgcn(
    const float* __restrict__ ent_emb,
    const float* __restrict__ w_tab,      // [B, NR]
    const int* __restrict__ click_seq,    // [B*S]
    const int* __restrict__ e1s,          // [B*S*K] precomputed
    const int* __restrict__ r0s,          // [B*S*K] precomputed
    const int* __restrict__ e2r1,         // [B*S*K*K] packed (e2<<6)|r1
    const float* __restrict__ agg_W,      // [D, D]
    const float* __restrict__ agg_b,      // [D]
    float* __restrict__ item)             // [B*S, D]
{
    __shared__ float wb[4][NR];
    __shared__ float Ws[4][D][D + 1];
    __shared__ float bs[4][D];
    __shared__ float Ms[4][K][D + 1];
    __shared__ float h1s[4][K][D + 1];
    __shared__ float h0s[4][D];
    __shared__ float A0s[4][D];
    __shared__ float M1s[4][D];
    __shared__ float p0s[4][K];

    const int tid = threadIdx.x;
    const int w = tid >> 6;             // wave in block, 0..3
    const int lane = tid & 63;
    const int p = blockIdx.x * 4 + w;   // pair id = b*S + s (64%4==0 -> same b)
    const int b = p >> 6;
    const int k = lane >> 3, j = lane & 7;

    // ---- index loads: all coalesced streams now (e2r1 warm from prep)
    const int e0 = click_seq[p];
    const int e1k = e1s[(long)p * K + k];
    const int r0k = r0s[(long)p * K + k];
    const int pk = __builtin_nontemporal_load(e2r1 + (long)p * (K * K) + lane);
    const int e2kj = ((unsigned)pk) >> 6;
    const int r1kj = pk & 63;

    // ---- per-wave LDS staging (wave-private slab; no cross-wave sharing)
    {
        const float4 wv = ((const float4*)agg_W)[lane];     // agg_W[4l..4l+3]
        int row = lane >> 2, col = (lane & 3) * 4;
        Ws[w][row][col] = wv.x; Ws[w][row][col + 1] = wv.y;
        Ws[w][row][col + 2] = wv.z; Ws[w][row][col + 3] = wv.w;
        wb[w][lane] = w_tab[b * NR + lane];
        if (lane < D) bs[w][lane] = agg_b[lane];
    }
    WAVE_LDS_FENCE();   // wb/Ws/bs visible to this wave

    // ---- hop-1 softmax over j (masks 1,2,4 stay inside the 8-lane j-group)
    float s1 = wb[w][r1kj];
    float m1 = s1;
    m1 = fmaxf(m1, __shfl_xor(m1, 1));
    m1 = fmaxf(m1, __shfl_xor(m1, 2));
    m1 = fmaxf(m1, __shfl_xor(m1, 4));
    float ex = expf(s1 - m1);
    float den = ex;
    den += __shfl_xor(den, 1);
    den += __shfl_xor(den, 2);
    den += __shfl_xor(den, 4);
    float p1 = ex / den;

    // ---- gather rows: q2 (own), q1 (group-shared), q0 (wave-shared)
    float q2r[D], q1r[D], q0r[D];
    {
        const float4* q2p = (const float4*)(ent_emb + (long)e2kj * D);
        float4 a0 = q2p[0], a1 = q2p[1], a2 = q2p[2], a3 = q2p[3];
        q2r[0]=a0.x; q2r[1]=a0.y; q2r[2]=a0.z; q2r[3]=a0.w;
        q2r[4]=a1.x; q2r[5]=a1.y; q2r[6]=a1.z; q2r[7]=a1.w;
        q2r[8]=a2.x; q2r[9]=a2.y; q2r[10]=a2.z; q2r[11]=a2.w;
        q2r[12]=a3.x; q2r[13]=a3.y; q2r[14]=a3.z; q2r[15]=a3.w;
    }
    {
        const float4* q1p = (const float4*)(ent_emb + (long)e1k * D);
        float4 a0 = q1p[0], a1 = q1p[1], a2 = q1p[2], a3 = q1p[3];
        q1r[0]=a0.x; q1r[1]=a0.y; q1r[2]=a0.z; q1r[3]=a0.w;
        q1r[4]=a1.x; q1r[5]=a1.y; q1r[6]=a1.z; q1r[7]=a1.w;
        q1r[8]=a2.x; q1r[9]=a2.y; q1r[10]=a2.z; q1r[11]=a2.w;
        q1r[12]=a3.x; q1r[13]=a3.y; q1r[14]=a3.z; q1r[15]=a3.w;
    }
    {
        const float4* q0p = (const float4*)(ent_emb + (long)e0 * D);
        float4 a0 = q0p[0], a1 = q0p[1], a2 = q0p[2], a3 = q0p[3];
        q0r[0]=a0.x; q0r[1]=a0.y; q0r[2]=a0.z; q0r[3]=a0.w;
        q0r[4]=a1.x; q0r[5]=a1.y; q0r[6]=a1.z; q0r[7]=a1.w;
        q0r[8]=a2.x; q0r[9]=a2.y; q0r[10]=a2.z; q0r[11]=a2.w;
        q0r[12]=a3.x; q0r[13]=a3.y; q0r[14]=a3.z; q0r[15]=a3.w;
    }

    // ---- hop-1 j-reduction (reduce-scatter, masks 1,2,4). Lane keeps the
    // half it will own; final 2 dims at dbase = 8(j&1)+4(j>>1&1)+2(j>>2&1).
    {
        float cur[16];
#pragma unroll
        for (int d = 0; d < 16; ++d) cur[d] = p1 * q2r[d];
        const bool b0 = (lane & 1), b1 = (lane & 2), b2 = (lane & 4);
        float n8[8];
#pragma unroll
        for (int d = 0; d < 8; ++d) {
            float snd = b0 ? cur[d] : cur[d + 8];
            float kp  = b0 ? cur[d + 8] : cur[d];
            n8[d] = kp + __shfl_xor(snd, 1);
        }
        float n4[4];
#pragma unroll
        for (int d = 0; d < 4; ++d) {
            float snd = b1 ? n8[d] : n8[d + 4];
            float kp  = b1 ? n8[d + 4] : n8[d];
            n4[d] = kp + __shfl_xor(snd, 2);
        }
        float a0 = (b2 ? n4[2] : n4[0]) + __shfl_xor(b2 ? n4[0] : n4[2], 4);
        float a1 = (b2 ? n4[3] : n4[1]) + __shfl_xor(b2 ? n4[1] : n4[3], 4);
        const int dbase = (b0 ? 8 : 0) + (b1 ? 4 : 0) + (b2 ? 2 : 0);
        Ms[w][k][dbase]     = q1r[dbase]     + a0;   // self + neigh_agg
        Ms[w][k][dbase + 1] = q1r[dbase + 1] + a1;
    }

    // ---- hop-0 softmax over k (masks 8,16,32 keep j fixed)
    float s0 = wb[w][r0k];
    float m0 = s0;
    m0 = fmaxf(m0, __shfl_xor(m0, 8));
    m0 = fmaxf(m0, __shfl_xor(m0, 16));
    m0 = fmaxf(m0, __shfl_xor(m0, 32));
    float e0x = expf(s0 - m0);
    float d0 = e0x;
    d0 += __shfl_xor(d0, 8);
    d0 += __shfl_xor(d0, 16);
    d0 += __shfl_xor(d0, 32);
    float p0 = e0x / d0;
    if (j == 0) p0s[w][k] = p0;

    // ---- ag0 = sum_k p0_k * q1[k]: reduce-scatter over k (masks 8,16,32);
    // identical values across j, so j==0 lanes deposit the 16 dims in A0s.
    {
        float cur[16];
#pragma unroll
        for (int d = 0; d < 16; ++d) cur[d] = p0 * q1r[d];
        const bool c0 = (lane & 8), c1 = (lane & 16), c2 = (lane & 32);
        float n8[8];
#pragma unroll
        for (int d = 0; d < 8; ++d) {
            float snd = c0 ? cur[d] : cur[d + 8];
            float kp  = c0 ? cur[d + 8] : cur[d];
            n8[d] = kp + __shfl_xor(snd, 8);
        }
        float n4[4];
#pragma unroll
        for (int d = 0; d < 4; ++d) {
            float snd = c1 ? n8[d] : n8[d + 4];
            float kp  = c1 ? n8[d + 4] : n8[d];
            n4[d] = kp + __shfl_xor(snd, 16);
        }
        float a0 = (c2 ? n4[2] : n4[0]) + __shfl_xor(c2 ? n4[0] : n4[2], 32);
        float a1 = (c2 ? n4[3] : n4[1]) + __shfl_xor(c2 ? n4[1] : n4[3], 32);
        const int dbase = (c0 ? 8 : 0) + (c1 ? 4 : 0) + (c2 ? 2 : 0);
        if (j == 0) { A0s[w][dbase] = a0; A0s[w][dbase + 1] = a1; }
    }
    WAVE_LDS_FENCE();   // Ms, A0s, p0s ready

    // ---- h1[k] = sigmoid(M[k] @ W + b): 128 outputs over 64 lanes (2 each)
#pragma unroll
    for (int o = lane; o < 128; o += 64) {
        int ko = o >> 4, dd = o & 15;
        float acc = bs[w][dd];
#pragma unroll
        for (int din = 0; din < D; ++din) acc += Ms[w][ko][din] * Ws[w][din][dd];
        h1s[w][ko][dd] = 1.0f / (1.0f + expf(-acc));
    }

    // ---- h0 = sigmoid((q0 + ag0) @ W + b)
    const int ddl = lane & 15;
    {
        float acc = bs[w][ddl];
#pragma unroll
        for (int din = 0; din < D; ++din)
            acc += (q0r[din] + A0s[w][din]) * Ws[w][din][ddl];
        if (lane < D) h0s[w][lane] = 1.0f / (1.0f + expf(-acc));
    }
    WAVE_LDS_FENCE();   // h1s, h0s ready

    // ---- iteration 1 input vector: M1 = h0 + sum_k p0_k * h1[k]
    if (lane < D) {
        float m = h0s[w][lane];
#pragma unroll
        for (int kk = 0; kk < K; ++kk) m += p0s[w][kk] * h1s[w][kk][lane];
        M1s[w][lane] = m;
    }
    WAVE_LDS_FENCE();   // M1s ready

    // ---- final: relu(tanh(M1 @ W + b))
    {
        float acc = bs[w][ddl];
#pragma unroll
        for (int din = 0; din < D; ++din) acc += M1s[w][din] * Ws[w][din][ddl];
        if (lane < D) item[(long)p * D + lane] = fmaxf(tanhf(acc), 0.0f);
    }
}

// ---------------------------------------------------------------------------
// Fused tail (one block per b, 256 threads):
//   - diffusion MLP 128-wide layers split-K across 2 half-threads (h=tid>>7):
//     chain length halves, waves/CU double (4 -> 8).
//   - fusion head runs CONCURRENTLY on waves 2-3 (sm stage, fus, hid, feat,
//     final dot are slotted into the MLP's barrier phases instead of after).
// ---------------------------------------------------------------------------
__global__ __launch_bounds__(256) void k_tail(
    const float* __restrict__ item,     // [B*S, D]
    const float* __restrict__ fc1_W, const float* __restrict__ fc1_b,
    const float* __restrict__ fc2_W, const float* __restrict__ fc2_b,
    const float* __restrict__ ent_emb, const int* __restrict__ v,
    const float* __restrict__ usr_emb, const float* __restrict__ noise_e,
    const int* __restrict__ u, const int* __restrict__ t_arr,
    const float* __restrict__ W1, const float* __restrict__ b1,
    const float* __restrict__ W2, const float* __restrict__ b2,
    const float* __restrict__ W3, const float* __restrict__ b3,
    const float* __restrict__ W4, const float* __restrict__ b4,
    const float* __restrict__ se1, const float* __restrict__ se2,
    const float* __restrict__ se3,
    const float* __restrict__ sa, const float* __restrict__ so,
    float* __restrict__ out)            // [B, 17]
{
    __shared__ float x0[D];
    __shared__ float v1[NUNITS], v2[NUNITS], v3[NUNITS];
    __shared__ float pp[2][NUNITS];
    __shared__ float sm[S][D + 1];
    __shared__ float fus[2 * D];
    __shared__ float hid[64];
    __shared__ float feat_s[D];

    const int b = blockIdx.x, tid = threadIdx.x;
    const int t = tid & 127, h = tid >> 7;
    const int ts = t_arr[b];

    // ---- phase 0: stage x0 (wave 0) + sm (wave 2)
    if (tid < D)
        x0[tid] = usr_emb[(long)u[b] * D + tid] * sa[ts] + noise_e[(long)b * D + tid] * so[ts];
    if (tid >= 128 && tid < 192) {
        int ss = tid - 128;
        const float4* ip = (const float4*)(item + ((long)b * S + ss) * D);
        float4 r0 = ip[0], r1 = ip[1], r2 = ip[2], r3 = ip[3];
        sm[ss][0]=r0.x;  sm[ss][1]=r0.y;  sm[ss][2]=r0.z;  sm[ss][3]=r0.w;
        sm[ss][4]=r1.x;  sm[ss][5]=r1.y;  sm[ss][6]=r1.z;  sm[ss][7]=r1.w;
        sm[ss][8]=r2.x;  sm[ss][9]=r2.y;  sm[ss][10]=r2.z; sm[ss][11]=r2.w;
        sm[ss][12]=r3.x; sm[ss][13]=r3.y; sm[ss][14]=r3.z; sm[ss][15]=r3.w;
    }
    __syncthreads();

    // ---- phase 1: L1 (waves 0-1, D-wide input: no split) + fus (wave 3)
    if (h == 0) {
        float a = b1[t] + se1[(long)ts * NUNITS + t];
#pragma unroll
        for (int i = 0; i < D; ++i) a += x0[i] * W1[i * NUNITS + t];
        v1[t] = fmaxf(a, 0.0f);
    } else if (tid >= 192 && tid < 192 + D) {
        int d = tid - 192;
        float sv = 0.0f, mv = -1e30f;
#pragma unroll
        for (int ss = 0; ss < S; ++ss) {
            float x = sm[ss][d];
            sv += x;
            mv = fmaxf(mv, x);
        }
        fus[d] = fmaxf(sv, 0.0f);
        fus[D + d] = fmaxf(mv, 0.0f);
    }
    __syncthreads();

    // ---- phase 2: L2 partials (all 256; each half sums 64 of 128)
    {
        float part = 0.0f;
        const float* wp = W2 + (long)(64 * h) * NUNITS + t;
#pragma unroll 8
        for (int i = 0; i < 64; ++i) part += v1[64 * h + i] * wp[(long)i * NUNITS];
        pp[h][t] = part;
    }
    __syncthreads();

    // ---- phase 3: v2 combine (waves 0-1) + hid (wave 2)
    if (tid < NUNITS) {
        v2[tid] = fmaxf(b2[tid] + se2[(long)ts * NUNITS + tid] + pp[0][tid] + pp[1][tid], 0.0f);
    } else if (tid < 192) {
        int o = tid - 128;
        float acc = fc1_b[o];
#pragma unroll
        for (int i = 0; i < 2 * D; ++i) acc += fus[i] * fc1_W[i * 64 + o];
        hid[o] = fmaxf(acc, 0.0f);
    }
    __syncthreads();

    // ---- phase 4: L3 partials
    {
        float part = 0.0f;
        const float* wp = W3 + (long)(64 * h) * NUNITS + t;
#pragma unroll 8
        for (int i = 0; i < 64; ++i) part += v2[64 * h + i] * wp[(long)i * NUNITS];
        pp[h][t] = part;
    }
    __syncthreads();

    // ---- phase 5: v3 combine (waves 0-1) + feat (wave 3)
    if (tid < NUNITS) {
        v3[tid] = fmaxf(b3[tid] + se3[(long)ts * NUNITS + tid] + pp[0][tid] + pp[1][tid], 0.0f);
    } else if (tid >= 192 && tid < 192 + D) {
        int d = tid - 192;
        float f = fc2_b[d];
#pragma unroll
        for (int i = 0; i < 64; ++i) f += hid[i] * fc2_W[i * D + d];
        feat_s[d] = fmaxf(f, 0.0f);
    }
    __syncthreads();

    // ---- phase 6: L4 partials (wave 0, lanes<32) + final dot (wave 3)
    if (tid < 32) {
        int o = tid & 15, hh = tid >> 4;
        float acc = 0.0f;
#pragma unroll
        for (int i = 0; i < 64; ++i) acc += v3[64 * hh + i] * W4[(64 * hh + i) * D + o];
        pp[hh][o] = acc;
    } else if (tid >= 192 && tid < 192 + D) {
        int d = tid - 192;
        float gv = feat_s[d] * ent_emb[(long)v[b] * D + d];
        gv += __shfl_xor(gv, 1);
        gv += __shfl_xor(gv, 2);
        gv += __shfl_xor(gv, 4);
        gv += __shfl_xor(gv, 8);
        if (d == 0) out[(long)b * 17] = 1.0f / (1.0f + expf(-gv));
    }
    __syncthreads();

    // ---- phase 7: diffusion output (no activation on the last layer)
    if (tid < D) out[(long)b * 17 + 1 + tid] = b4[tid] + pp[0][tid] + pp[1][tid];
}

// ---------------------------------------------------------------------------
extern "C" void kernel_launch(void* const* d_in, const int* in_sizes, int n_in,
                              void* d_out, int out_size, void* d_ws, size_t ws_size,
                              hipStream_t stream) {
    const float* usr_emb = (const float*)d_in[0];
    const float* ent_emb = (const float*)d_in[1];
    const float* rel_emb = (const float*)d_in[2];
    const float* agg_W   = (const float*)d_in[3];
    const float* agg_b   = (const float*)d_in[4];
    const float* fc1_W   = (const float*)d_in[5];
    const float* fc1_b   = (const float*)d_in[6];
    const float* fc2_W   = (const float*)d_in[7];
    const float* fc2_b   = (const float*)d_in[8];
    const float* mlp_W1  = (const float*)d_in[9];
    const float* mlp_b1  = (const float*)d_in[10];
    const float* mlp_W2  = (const float*)d_in[11];
    const float* mlp_b2  = (const float*)d_in[12];
    const float* mlp_W3  = (const float*)d_in[13];
    const float* mlp_b3  = (const float*)d_in[14];
    const float* mlp_W4  = (const float*)d_in[15];
    const float* mlp_b4  = (const float*)d_in[16];
    const float* se1     = (const float*)d_in[17];
    const float* se2     = (const float*)d_in[18];
    const float* se3     = (const float*)d_in[19];
    const float* noise_e = (const float*)d_in[20];
    const int* u         = (const int*)d_in[21];
    const int* v         = (const int*)d_in[22];
    const int* click_seq = (const int*)d_in[23];
    const int* adj_ent   = (const int*)d_in[24];
    const int* adj_rel   = (const int*)d_in[25];
    const int* t         = (const int*)d_in[26];
    float* out = (float*)d_out;

    float* ws = (float*)d_ws;
    float* w_tab = ws;                         // B*NR floats
    float* sa    = w_tab + B * NR;             // 128 floats (NSTEPS used)
    float* so    = sa + 128;                   // 128 floats
    float* item  = so + 128;                   // B*S*D floats (2 MB)
    int*   e1s   = (int*)(item + B * S * D);   // B*S*K ints (1 MB)
    int*   r0s   = e1s + B * S * K;            // B*S*K ints (1 MB)
    int*   e2r1  = r0s + B * S * K;            // B*S*K*K ints (8 MB, packed)

    k_prep_all<<<B, 256, 0, stream>>>(usr_emb, rel_emb, u, click_seq, adj_ent, adj_rel,
                                      w_tab, e1s, r0s, e2r1, sa, so);
    k_kgcn<<<(B * S) / 4, 256, 0, stream>>>(ent_emb, w_tab, click_seq,
                                            e1s, r0s, e2r1, agg_W, agg_b, item);
    k_tail<<<B, 256, 0, stream>>>(item, fc1_W, fc1_b, fc2_W, fc2_b, ent_emb, v,
                                  usr_emb, noise_e, u, t, mlp_W1, mlp_b1, mlp_W2, mlp_b2,
                                  mlp_W3, mlp_b3, mlp_W4, mlp_b4, se1, se2, se3, sa, so, out);
}